// Round 5
// baseline (88.085 us; speedup 1.0000x reference)
//
#include <hip/hip_runtime.h>
#include <hip/hip_cooperative_groups.h>
#include <math.h>

namespace cg = cooperative_groups;

#define SZ 256
#define KPTS 64
#define NBLK (4 * SZ)              // 1024 blocks: (bn, row i)
#define K_SIGN 100000.0f
#define EPS_C 1e-5f
#define INV_2PI 0.15915494309189535f
#define PI_F 3.14159265358979323846f

__device__ __forceinline__ float fast_rcp(float x)  { return __builtin_amdgcn_rcpf(x); }
__device__ __forceinline__ float fast_sqrt(float x) { return __builtin_amdgcn_sqrtf(x); }
__device__ __forceinline__ float fast_rsq(float x)  { return __builtin_amdgcn_rsqf(x); }

// tanh(u) = 1 - 2/(exp(2u)+1); exp(inf)->1, exp(0)->-1, no NaN.
__device__ __forceinline__ float fast_tanh_big(float x2k) {
    float t = __expf(x2k);
    return fmaf(-2.0f, fast_rcp(t + 1.0f), 1.0f);
}

// acos approx (Abramowitz-Stegun 4.4.45), max err ~6.7e-5 rad.
__device__ __forceinline__ float fast_acos(float x) {
    float ax = fabsf(x);
    float s  = fast_sqrt(1.0f - ax);
    float p  = s * fmaf(ax, fmaf(ax, fmaf(ax, -0.0187292994f, 0.0742610037f),
                                  -0.2121143937f), 1.5707288f);
    return (x >= 0.0f) ? p : (PI_F - p);
}

// One fused cooperative kernel:
//   phase 1: per-pixel prod (kept in register), per-block max -> ws[blk]
//   grid sync
//   phase 2: every block reduces ws[0..1023] -> global max, writes prod/max.
// d_ws layout: ws[blk] = per-block max (1024 floats), fully rewritten each call.
__global__ __launch_bounds__(256) void contour_fused_kernel(
    const float* __restrict__ contour,   // [4][64][2]
    float* __restrict__ out,             // [4][256][256]
    float* __restrict__ ws)              // [1024]
{
    __shared__ float cx[KPTS + 1];
    __shared__ float cy[KPTS + 1];
    __shared__ float wred[4];
    __shared__ float smax;

    const int blk = blockIdx.x;
    const int i   = blk & 255;           // row
    const int bn  = blk >> 8;            // which contour
    const int t   = threadIdx.x;         // pixel column j

    if (t < KPTS) {
        float x = contour[(bn * KPTS + t) * 2 + 0];
        float y = contour[(bn * KPTS + t) * 2 + 1];
        cx[t] = x; cy[t] = y;
        if (t == 0) { cx[KPTS] = x; cy[KPTS] = y; }   // wraparound dup
    }
    __syncthreads();

    const float mx = (float)i * (1.0f / (float)SZ);
    const float my = (float)t * (1.0f / (float)SZ);

    float dxc  = cx[0] - mx;
    float dyc  = cy[0] - my;
    float n2c  = fmaf(dxc, dxc, dyc * dyc);
    float invc = fast_rsq(n2c);
    float minn2 = n2c;                   // min of squared norms; sqrt once at end
    float acc   = 0.0f;

    #pragma unroll 8
    for (int k = 0; k < KPTS; ++k) {
        const float dxn  = cx[k + 1] - mx;   // LDS broadcast reads
        const float dyn  = cy[k + 1] - my;
        const float n2n  = fmaf(dxn, dxn, dyn * dyn);
        const float invn = fast_rsq(n2n);
        minn2 = fminf(minn2, n2n);

        const float cross = dyc * dxn - dxc * dyn;
        const float sgn   = fast_tanh_big((2.0f * K_SIGN) * cross);

        const float dot = fmaf(dxc, dxn, dyc * dyn);
        float cosang = dot * invc * invn;
        cosang = fminf(fmaxf(cosang, -1.0f + EPS_C), 1.0f - EPS_C);  // v_med3
        const float ang = fast_acos(cosang);

        acc = fmaf(sgn, ang, acc);

        dxc = dxn; dyc = dyn; invc = invn;
    }

    const float prod = fabsf(acc) * INV_2PI * fast_sqrt(minn2);

    // per-block max -> ws[blk] (plain store, no contention)
    float wmax = prod;
    #pragma unroll
    for (int off = 32; off > 0; off >>= 1)
        wmax = fmaxf(wmax, __shfl_down(wmax, off, 64));
    if ((t & 63) == 0) wred[t >> 6] = wmax;
    __syncthreads();
    if (t == 0)
        ws[blk] = fmaxf(fmaxf(wred[0], wred[1]), fmaxf(wred[2], wred[3]));

    cg::this_grid().sync();

    // every block reduces the 1024 block-maxes (L2-hit reads)
    float m = fmaxf(fmaxf(ws[t], ws[t + 256]), fmaxf(ws[t + 512], ws[t + 768]));
    #pragma unroll
    for (int off = 32; off > 0; off >>= 1)
        m = fmaxf(m, __shfl_down(m, off, 64));
    if ((t & 63) == 0) wred[t >> 6] = m;
    __syncthreads();
    if (t == 0)
        smax = fmaxf(fmaxf(wred[0], wred[1]), fmaxf(wred[2], wred[3]));
    __syncthreads();

    out[((bn << 8) + i) * SZ + t] = prod / smax;
}

extern "C" void kernel_launch(void* const* d_in, const int* in_sizes, int n_in,
                              void* d_out, int out_size, void* d_ws, size_t ws_size,
                              hipStream_t stream)
{
    const float* contour = (const float*)d_in[0];   // [2][2][64][2] fp32
    float* out = (float*)d_out;                     // [2][2][256][256] fp32
    float* ws  = (float*)d_ws;

    void* args[] = { (void*)&contour, (void*)&out, (void*)&ws };
    hipLaunchCooperativeKernel((const void*)contour_fused_kernel,
                               dim3(NBLK), dim3(SZ), args, 0, stream);
}

// Round 6
// 23.874 us; speedup vs baseline: 3.6895x; 3.6895x over previous
//
#include <hip/hip_runtime.h>
#include <math.h>

#define SZ 256
#define KPTS 64
#define GROUPS 4
#define SEGS_PER (KPTS / GROUPS)   // 16 segments per thread
#define NBLK (4 * SZ * GROUPS)     // 4096 prod blocks
#define K_SIGN 100000.0f
#define EPS_C 1e-5f
#define INV_2PI 0.15915494309189535f
#define PI_F 3.14159265358979323846f
// 2*K_SIGN*log2(e): tanh(2K*c) via exp2
#define K2_LOG2E 288539.00817779269f

__device__ __forceinline__ float fast_rcp(float x)  { return __builtin_amdgcn_rcpf(x); }
__device__ __forceinline__ float fast_sqrt(float x) { return __builtin_amdgcn_sqrtf(x); }
__device__ __forceinline__ float fast_rsq(float x)  { return __builtin_amdgcn_rsqf(x); }
__device__ __forceinline__ float fast_exp2(float x) { return __builtin_amdgcn_exp2f(x); }

// tanh(2K*cross) = 1 - 2/(exp2(2K*log2e*cross)+1); saturates cleanly to +/-1.
__device__ __forceinline__ float fast_tanh_k(float cross) {
    float t = fast_exp2(K2_LOG2E * cross);
    return fmaf(-2.0f, fast_rcp(t + 1.0f), 1.0f);
}

// acos approx (Abramowitz-Stegun 4.4.45), max err ~6.7e-5 rad.
__device__ __forceinline__ float fast_acos(float x) {
    float ax = fabsf(x);
    float s  = fast_sqrt(1.0f - ax);
    float p  = s * fmaf(ax, fmaf(ax, fmaf(ax, -0.0187292994f, 0.0742610037f),
                                  -0.2121143937f), 1.5707288f);
    return (x >= 0.0f) ? p : (PI_F - p);
}

// d_ws: ws[blk] = per-block max, blk in [0,4096); fully rewritten every call.

// grid = bn(4) * i(256) * jq(4) = 4096 blocks, block = 256 threads.
// thread t: g = t&3 (16-segment group), jloc = t>>2 -> pixel j = jq*64+jloc.
__global__ __launch_bounds__(256) void contour_prod_kernel(
    const float* __restrict__ contour,   // [4][64][2]
    float* __restrict__ out,             // [4][256][256] unnormalized
    float* __restrict__ ws)              // [4096] per-block maxes
{
    __shared__ float cx[KPTS + 1];
    __shared__ float cy[KPTS + 1];
    __shared__ float wred[4];

    const int blk = blockIdx.x;
    const int jq  = blk & 3;
    const int i   = (blk >> 2) & 255;
    const int bn  = blk >> 10;

    const int t = threadIdx.x;
    if (t < KPTS) {
        float x = contour[(bn * KPTS + t) * 2 + 0];
        float y = contour[(bn * KPTS + t) * 2 + 1];
        cx[t] = x; cy[t] = y;
        if (t == 0) { cx[KPTS] = x; cy[KPTS] = y; }   // wraparound dup
    }
    __syncthreads();

    const int g    = t & 3;
    const int jloc = t >> 2;
    const int j    = (jq << 6) + jloc;

    const float mx = (float)i * (1.0f / (float)SZ);
    const float my = (float)j * (1.0f / (float)SZ);

    const int base = g * SEGS_PER;

    float dxc   = cx[base] - mx;
    float dyc   = cy[base] - my;
    float n2c   = fmaf(dxc, dxc, dyc * dyc);
    float invc  = fast_rsq(n2c);
    float minn2 = n2c;                  // min of squared norms; sqrt at the end
    float acc   = 0.0f;

    #pragma unroll
    for (int kk = 0; kk < SEGS_PER; ++kk) {
        const float dxn  = cx[base + kk + 1] - mx;
        const float dyn  = cy[base + kk + 1] - my;
        const float n2n  = fmaf(dxn, dxn, dyn * dyn);
        const float invn = fast_rsq(n2n);
        minn2 = fminf(minn2, n2n);

        const float cross = dyc * dxn - dxc * dyn;
        const float sgn   = fast_tanh_k(cross);

        const float dot = fmaf(dxc, dxn, dyc * dyn);
        float cosang = dot * invc * invn;
        cosang = fminf(fmaxf(cosang, -1.0f + EPS_C), 1.0f - EPS_C);  // v_med3
        const float ang = fast_acos(cosang);

        acc = fmaf(sgn, ang, acc);

        dxc = dxn; dyc = dyn; invc = invn;
    }

    // combine 4 segment-groups of the pixel
    acc += __shfl_xor(acc, 1, 64);
    acc += __shfl_xor(acc, 2, 64);
    minn2 = fminf(minn2, __shfl_xor(minn2, 1, 64));
    minn2 = fminf(minn2, __shfl_xor(minn2, 2, 64));

    const float prod = fabsf(acc) * INV_2PI * fast_sqrt(minn2);
    if (g == 0)
        out[((bn << 8) + i) * SZ + j] = prod;

    // block max -> plain store
    float wmax = prod;
    #pragma unroll
    for (int off = 32; off > 0; off >>= 1)
        wmax = fmaxf(wmax, __shfl_down(wmax, off, 64));
    if ((t & 63) == 0) wred[t >> 6] = wmax;
    __syncthreads();
    if (t == 0)
        ws[blk] = fmaxf(fmaxf(wred[0], wred[1]), fmaxf(wred[2], wred[3]));
}

// 256 blocks x 256 threads. Each block re-reduces ws[0..4095] (L2-hit, 16 KB),
// then normalizes its 1024-pixel chunk (float4 per thread).
__global__ __launch_bounds__(256) void contour_norm_kernel(
    float4* __restrict__ out,
    const float* __restrict__ ws)
{
    __shared__ float wred[4];
    __shared__ float smax;

    const int t = threadIdx.x;
    const float4* w4 = (const float4*)ws;   // 1024 float4

    float m = 0.0f;                          // prod >= 0
    #pragma unroll
    for (int r = 0; r < 4; ++r) {
        float4 v = w4[t + (r << 8)];
        m = fmaxf(m, fmaxf(fmaxf(v.x, v.y), fmaxf(v.z, v.w)));
    }
    #pragma unroll
    for (int off = 32; off > 0; off >>= 1)
        m = fmaxf(m, __shfl_down(m, off, 64));
    if ((t & 63) == 0) wred[t >> 6] = m;
    __syncthreads();
    if (t == 0)
        smax = fmaxf(fmaxf(wred[0], wred[1]), fmaxf(wred[2], wred[3]));
    __syncthreads();

    const float inv = 1.0f / smax;           // one IEEE divide, <=2ulp vs per-elem
    const int idx = blockIdx.x * 256 + t;
    float4 v = out[idx];
    v.x *= inv; v.y *= inv; v.z *= inv; v.w *= inv;
    out[idx] = v;
}

extern "C" void kernel_launch(void* const* d_in, const int* in_sizes, int n_in,
                              void* d_out, int out_size, void* d_ws, size_t ws_size,
                              hipStream_t stream)
{
    const float* contour = (const float*)d_in[0];   // [2][2][64][2] fp32
    float* out = (float*)d_out;                     // [2][2][256][256] fp32
    float* ws  = (float*)d_ws;

    contour_prod_kernel<<<NBLK, SZ, 0, stream>>>(contour, out, ws);
    contour_norm_kernel<<<out_size / 4 / 256, 256, 0, stream>>>((float4*)out, ws);
}